// Round 2
// baseline (3609.759 us; speedup 1.0000x reference)
//
#include <hip/hip_runtime.h>
#include <hip/hip_bf16.h>

#define NCHUNK 8

__device__ __forceinline__ float siluf(float x) {
    return x / (1.0f + __expf(-x));
}

// ---------------- init: species + s = W_embed[z], v = 0, deg = 0 ----------------
__global__ void k_init(const float* __restrict__ attrs, const float* __restrict__ Wemb,
                       int* __restrict__ species, int* __restrict__ deg,
                       float* __restrict__ s, float* __restrict__ v, int N) {
    int lane = threadIdx.x;
    int n0 = blockIdx.x * 64;
    for (int r = 0; r < 64; r++) {
        int n = n0 + r;
        if (n >= N) break;
        float a = (lane < 10) ? attrs[n * 10 + lane] : 0.0f;
        unsigned long long m = __ballot(a > 0.5f);
        int z = __ffsll(m) - 1;
        if (lane == 0) { species[n] = z; deg[n] = 0; }
        s[n * 64 + lane] = Wemb[z * 64 + lane];
        v[n * 192 + lane] = 0.0f;
        v[n * 192 + 64 + lane] = 0.0f;
        v[n * 192 + 128 + lane] = 0.0f;
    }
}

// ---------------- counting sort by receiver ----------------
__global__ void k_hist(const int* __restrict__ ei, int* __restrict__ deg, int E) {
    int e = blockIdx.x * 256 + threadIdx.x;
    if (e < E) atomicAdd(&deg[ei[E + e]], 1);
}

__global__ void k_scan(const int* __restrict__ deg, int* __restrict__ rowptr,
                       int* __restrict__ cursor, int N) {
    __shared__ int part[1024];
    int t = threadIdx.x;
    int chunk = (N + 1023) / 1024;
    int lo = t * chunk, hi = min(lo + chunk, N);
    int sum = 0;
    for (int i = lo; i < hi; i++) sum += deg[i];
    part[t] = sum;
    __syncthreads();
    for (int off = 1; off < 1024; off <<= 1) {
        int add = (t >= off) ? part[t - off] : 0;
        __syncthreads();
        part[t] += add;
        __syncthreads();
    }
    int run = (t > 0) ? part[t - 1] : 0;
    for (int i = lo; i < hi; i++) { rowptr[i] = run; cursor[i] = run; run += deg[i]; }
    if (t == 1023) rowptr[N] = part[1023];
}

__global__ void k_perm(const int* __restrict__ ei, int* __restrict__ cursor,
                       int* __restrict__ perm, int E) {
    int e = blockIdx.x * 256 + threadIdx.x;
    if (e < E) {
        int r = ei[E + e];
        int pos = atomicAdd(&cursor[r], 1);
        perm[pos] = e;
    }
}

// ---------------- geometry + radial basis on SORTED edge order ----------------
__global__ void k_geom(const int* __restrict__ ei, const int* __restrict__ perm,
                       const float* __restrict__ pos, const float* __restrict__ shifts,
                       float4* __restrict__ geo, float* __restrict__ efT,
                       int* __restrict__ snd_s, int E) {
    int j = blockIdx.x * 64 + threadIdx.x;
    if (j >= E) return;
    int e = perm[j];
    int snd = ei[e], rcv = ei[E + e];
    float dx = pos[rcv * 3 + 0] - pos[snd * 3 + 0] + shifts[e * 3 + 0];
    float dy = pos[rcv * 3 + 1] - pos[snd * 3 + 1] + shifts[e * 3 + 1];
    float dz = pos[rcv * 3 + 2] - pos[snd * 3 + 2] + shifts[e * 3 + 2];
    float r = sqrtf(dx * dx + dy * dy + dz * dz);
    float rin = 1.0f / (r + 1e-9f);
    const float SQ3 = 1.7320508075688772f;
    geo[j] = make_float4(SQ3 * dx * rin, SQ3 * dy * rin, SQ3 * dz * rin, 0.0f);
    snd_s[j] = snd;
    float u = r * 0.2f;
    float env = 0.0f;
    if (u < 1.0f) {
        float u2 = u * u;
        float u6 = u2 * u2 * u2;
        env = 1.0f - 28.0f * u6 + 48.0f * u6 * u - 21.0f * u6 * u2;
    }
    const float PIF = 3.14159265358979f;
    float x = PIF * u;
    float sp = __sinf(x), cp = __cosf(x);
    float coef = 0.6324555320336759f * rin * env;
    float sm1 = 0.0f, scur = sp, twoc = 2.0f * cp;
    #pragma unroll
    for (int k = 0; k < 8; k++) {
        efT[k * (size_t)E + j] = coef * scur;
        float nxt = twoc * scur - sm1;
        sm1 = scur; scur = nxt;
    }
}

// ---------------- generic 64-node tile GEMV ----------------
__device__ __forceinline__ void tile_mv64(const float* __restrict__ in, int istride,
                                          const float* __restrict__ W,
                                          float* __restrict__ outp, int ostride,
                                          float* __restrict__ packf, int comp,
                                          int n0, int nv, float* lds, int lane) {
    for (int r = 0; r < nv; r++) lds[r * 65 + lane] = in[(size_t)(n0 + r) * istride + lane];
    __syncthreads();
    float acc[64];
    #pragma unroll
    for (int d = 0; d < 64; d++) acc[d] = 0.0f;
    for (int c = 0; c < 64; c++) {
        float x = lds[lane * 65 + c];
        const float* wr = W + c * 64;
        #pragma unroll
        for (int d = 0; d < 64; d++) acc[d] = fmaf(x, wr[d], acc[d]);
    }
    __syncthreads();
    #pragma unroll
    for (int d = 0; d < 64; d++) lds[lane * 65 + d] = acc[d];
    __syncthreads();
    for (int r = 0; r < nv; r++) {
        float val = lds[r * 65 + lane];
        if (outp) outp[(size_t)(n0 + r) * ostride + lane] = val;
        if (packf) packf[(((size_t)(n0 + r)) * 64 + lane) * 4 + comp] = val;
    }
    __syncthreads();
}

// 4 GEMVs: s @ Ws and v[x] @ Wv; optionally into packed float4 layout
__global__ void k_4mv(const float* __restrict__ ins, const float* __restrict__ inv,
                      const float* __restrict__ Ws, const float* __restrict__ Wv,
                      float* __restrict__ outs, float* __restrict__ outv,
                      float* __restrict__ packf, int N) {
    __shared__ float lds[64 * 65];
    int lane = threadIdx.x;
    int n0 = blockIdx.x * 64;
    int nv = min(64, N - n0);
    tile_mv64(ins, 64, Ws, outs, 64, packf, 0, n0, nv, lds, lane);
    for (int x = 0; x < 3; x++)
        tile_mv64(inv + x * 64, 192, Wv, outv ? outv + x * 64 : nullptr, 192,
                  packf, 1 + x, n0, nv, lds, lane);
}

// ---------------- message kernel: radial MLP + message -> coalesced store ----------------
__global__ void k_msg(const int* __restrict__ rowptr, int na, int nb,
                      const float* __restrict__ efT, const float4* __restrict__ geo,
                      const int* __restrict__ snd_s, const float4* __restrict__ pack,
                      const float* __restrict__ RW1, const float* __restrict__ RW2,
                      const float* __restrict__ RW3, float4* __restrict__ msg,
                      int cap, int E) {
    __shared__ float lh[64 * 64];
    __shared__ float lw[64 * 41];
    const int lane = threadIdx.x;
    const int Jlo = rowptr[na], Jhi = rowptr[nb];
    const int j0 = Jlo + blockIdx.x * 64;
    if (j0 >= Jhi) return;
    const int j = j0 + lane;
    const bool vj = (j < Jhi);

    float ef[8];
    #pragma unroll
    for (int k = 0; k < 8; k++) ef[k] = vj ? efT[k * (size_t)E + j] : 0.0f;
    float h[64];
    #pragma unroll
    for (int d = 0; d < 64; d++) h[d] = 0.0f;
    #pragma unroll
    for (int k = 0; k < 8; k++) {
        float x = ef[k];
        const float* wr = RW1 + k * 64;
        #pragma unroll
        for (int d = 0; d < 64; d++) h[d] = fmaf(x, wr[d], h[d]);
    }
    #pragma unroll
    for (int d = 0; d < 64; d++) lh[d * 64 + lane] = siluf(h[d]);
    __syncthreads();

    #pragma unroll
    for (int d = 0; d < 64; d++) h[d] = 0.0f;
    for (int c = 0; c < 64; c++) {
        float x = lh[c * 64 + lane];
        const float* wr = RW2 + c * 64;
        #pragma unroll
        for (int d = 0; d < 64; d++) h[d] = fmaf(x, wr[d], h[d]);
    }
    __syncthreads();
    #pragma unroll
    for (int d = 0; d < 64; d++) lh[d * 64 + lane] = siluf(h[d]);
    __syncthreads();

    const float inv32 = 1.0f / 32.0f;
    const float is3 = 0.5773502691896258f;
    const float is2 = 0.7071067811865476f;
    const int elb = lane >> 3;
    const int cj = lane & 7;

    for (int cc = 0; cc < 8; cc++) {
        float w[40];
        #pragma unroll
        for (int q = 0; q < 40; q++) w[q] = 0.0f;
        for (int c = 0; c < 64; c++) {
            float x = lh[c * 64 + lane];
            const float* wr = RW3 + c * 320 + cc * 8;
            #pragma unroll
            for (int q = 0; q < 5; q++) {
                #pragma unroll
                for (int jj = 0; jj < 8; jj++)
                    w[q * 8 + jj] = fmaf(x, wr[q * 64 + jj], w[q * 8 + jj]);
            }
        }
        __syncthreads();
        #pragma unroll
        for (int q = 0; q < 5; q++) {
            #pragma unroll
            for (int jj = 0; jj < 8; jj++)
                lw[lane * 41 + q * 8 + jj] = w[q * 8 + jj];
        }
        __syncthreads();

        const int c = cc * 8 + cj;
        for (int t = 0; t < 8; t++) {
            int el = t * 8 + elb;
            int e2 = j0 + el;
            if (e2 < Jhi && (e2 - Jlo) < cap) {
                int snd = snd_s[e2];
                float4 g = geo[e2];
                float w00  = lw[el * 41 + cj];
                float w110 = lw[el * 41 + 8 + cj];
                float w011 = lw[el * 41 + 16 + cj];
                float w101 = lw[el * 41 + 24 + cj];
                float w111 = lw[el * 41 + 32 + cj];
                float4 pv = pack[(size_t)snd * 64 + c];  // (s_up, v0, v1, v2)
                float dvy = pv.y * g.x + pv.z * g.y + pv.w * g.z;
                float m0 = (w00 * pv.x + w110 * dvy * is3) * inv32;
                float cxv = pv.z * g.z - pv.w * g.y;
                float cyv = pv.w * g.x - pv.y * g.z;
                float czv = pv.y * g.y - pv.z * g.x;
                float m1x = (w011 * pv.x * g.x + w101 * pv.y + w111 * cxv * is2) * inv32;
                float m1y = (w011 * pv.x * g.y + w101 * pv.z + w111 * cyv * is2) * inv32;
                float m1z = (w011 * pv.x * g.z + w101 * pv.w + w111 * czv * is2) * inv32;
                msg[((size_t)(e2 - Jlo)) * 64 + c] = make_float4(m0, m1x, m1y, m1z);
            }
        }
        __syncthreads();
    }
}

// ---------------- CSR aggregation: wave per node, lane = channel ----------------
__global__ void k_agg(const float4* __restrict__ msg, const int* __restrict__ rowptr,
                      float* __restrict__ agg0, float* __restrict__ agg1,
                      int na, int nb, int cap) {
    int n = na + blockIdx.x * 4 + (threadIdx.x >> 6);
    int lane = threadIdx.x & 63;
    if (n >= nb) return;
    int Jlo = rowptr[na];
    int j0 = rowptr[n], j1 = rowptr[n + 1];
    float a0 = 0.0f, a1 = 0.0f, a2 = 0.0f, a3 = 0.0f;
    for (int j = j0; j < j1; j++) {
        int idx = j - Jlo;
        if (idx >= cap) break;
        float4 m = msg[(size_t)idx * 64 + lane];
        a0 += m.x; a1 += m.y; a2 += m.z; a3 += m.w;
    }
    size_t nbase = (size_t)n;
    agg0[nbase * 64 + lane] = a0;
    agg1[nbase * 192 + lane] = a1;
    agg1[nbase * 192 + 64 + lane] = a2;
    agg1[nbase * 192 + 128 + lane] = a3;
}

// ---------------- species-dependent skip connections (wave = node) ----------------
__global__ void k_sc(const float* __restrict__ s, const float* __restrict__ v,
                     const int* __restrict__ species, const float* __restrict__ Wsc_s,
                     const float* __restrict__ Wsc_v, float* __restrict__ sc_s,
                     float* __restrict__ sc_v, int N) {
    int n = blockIdx.x;
    if (n >= N) return;
    int lane = threadIdx.x;
    int z = species[n];
    const float* Ws = Wsc_s + (size_t)z * 4096;
    const float* Wv = Wsc_v + (size_t)z * 4096;
    size_t nb = (size_t)n;
    float sreg = s[nb * 64 + lane];
    float acc = 0.0f;
    for (int c = 0; c < 64; c++)
        acc = fmaf(__shfl(sreg, c), Ws[c * 64 + lane], acc);
    sc_s[nb * 64 + lane] = acc;
    for (int x = 0; x < 3; x++) {
        float vreg = v[nb * 192 + x * 64 + lane];
        float av = 0.0f;
        for (int c = 0; c < 64; c++)
            av = fmaf(__shfl(vreg, c), Wv[c * 64 + lane], av);
        sc_v[nb * 192 + x * 64 + lane] = av;
    }
}

// ---------------- prod_s -> new s + output slot ----------------
__global__ void k_prod_s(const float* __restrict__ ms, const float* __restrict__ mv,
                         const float* __restrict__ P0l, const int* __restrict__ species,
                         const float* __restrict__ Wp, const float* __restrict__ sc_s,
                         float* __restrict__ s, float* __restrict__ out,
                         int N, int layer, int L) {
    __shared__ float lds[64 * 65];
    int lane = threadIdx.x;
    int n0 = blockIdx.x * 64;
    int nv = min(64, N - n0);
    for (int r = 0; r < nv; r++) {
        size_t n = n0 + r;
        int z = species[n];
        float msv = ms[n * 64 + lane];
        float a = mv[n * 192 + lane];
        float b = mv[n * 192 + 64 + lane];
        float cq = mv[n * 192 + 128 + lane];
        float mq = a * a + b * b + cq * cq;
        const float* p = P0l + ((size_t)z * 64 + lane) * 3;
        lds[r * 65 + lane] = p[0] * msv + p[1] * msv * msv + p[2] * mq;
    }
    __syncthreads();
    float acc[64];
    #pragma unroll
    for (int d = 0; d < 64; d++) acc[d] = 0.0f;
    for (int c = 0; c < 64; c++) {
        float x = lds[lane * 65 + c];
        const float* wr = Wp + c * 64;
        #pragma unroll
        for (int d = 0; d < 64; d++) acc[d] = fmaf(x, wr[d], acc[d]);
    }
    __syncthreads();
    #pragma unroll
    for (int d = 0; d < 64; d++) lds[lane * 65 + d] = acc[d];
    __syncthreads();
    for (int r = 0; r < nv; r++) {
        size_t n = n0 + r;
        float val = lds[r * 65 + lane] + sc_s[n * 64 + lane];
        s[n * 64 + lane] = val;
        out[n * (size_t)(L * 64) + layer * 64 + lane] = val;
    }
}

// ---------------- prod_v -> new v ----------------
__global__ void k_prod_v(const float* __restrict__ ms, const float* __restrict__ mv,
                         const float* __restrict__ P1l, const int* __restrict__ species,
                         const float* __restrict__ Wp, const float* __restrict__ sc_v,
                         float* __restrict__ v, int N) {
    __shared__ float lds[64 * 65];
    int lane = threadIdx.x;
    int n0 = blockIdx.x * 64;
    int nv = min(64, N - n0);
    for (int x = 0; x < 3; x++) {
        for (int r = 0; r < nv; r++) {
            size_t n = n0 + r;
            int z = species[n];
            float msv = ms[n * 64 + lane];
            float mvv = mv[n * 192 + x * 64 + lane];
            const float* q = P1l + ((size_t)z * 64 + lane) * 2;
            lds[r * 65 + lane] = (q[0] + q[1] * msv) * mvv;
        }
        __syncthreads();
        float acc[64];
        #pragma unroll
        for (int d = 0; d < 64; d++) acc[d] = 0.0f;
        for (int c = 0; c < 64; c++) {
            float xx = lds[lane * 65 + c];
            const float* wr = Wp + c * 64;
            #pragma unroll
            for (int d = 0; d < 64; d++) acc[d] = fmaf(xx, wr[d], acc[d]);
        }
        __syncthreads();
        #pragma unroll
        for (int d = 0; d < 64; d++) lds[lane * 65 + d] = acc[d];
        __syncthreads();
        for (int r = 0; r < nv; r++) {
            size_t n = n0 + r;
            v[n * 192 + x * 64 + lane] = lds[r * 65 + lane] + sc_v[n * 192 + x * 64 + lane];
        }
        __syncthreads();
    }
}

extern "C" void kernel_launch(void* const* d_in, const int* in_sizes, int n_in,
                              void* d_out, int out_size, void* d_ws, size_t ws_size,
                              hipStream_t stream) {
    const float* node_attrs = (const float*)d_in[0];
    const float* atom_pos   = (const float*)d_in[1];
    const float* shifts     = (const float*)d_in[2];
    const float* W_embed    = (const float*)d_in[3];
    const float* Wup_s      = (const float*)d_in[4];
    const float* Wup_v      = (const float*)d_in[5];
    const float* RW1        = (const float*)d_in[6];
    const float* RW2        = (const float*)d_in[7];
    const float* RW3        = (const float*)d_in[8];
    const float* Wout_s     = (const float*)d_in[9];
    const float* Wout_v     = (const float*)d_in[10];
    const float* Wsc_s      = (const float*)d_in[11];
    const float* Wsc_v      = (const float*)d_in[12];
    const float* P0         = (const float*)d_in[13];
    const float* P1         = (const float*)d_in[14];
    const float* Wprod_s    = (const float*)d_in[15];
    const float* Wprod_v    = (const float*)d_in[16];
    const int*   ei         = (const int*)d_in[17];

    const int N = in_sizes[0] / 10;
    const int E = in_sizes[17] / 2;
    const int L = in_sizes[4] / 4096;
    float* out = (float*)d_out;

    char* wsb = (char*)d_ws;
    size_t off = 0;
    auto alloci = [&](size_t n) {
        int* p = (int*)(wsb + off);
        off = (off + n * 4 + 255) / 256 * 256;
        return p;
    };
    auto allocf = [&](size_t n) {
        float* p = (float*)(wsb + off);
        off = (off + n * 4 + 255) / 256 * 256;
        return p;
    };
    int* species = alloci(N);
    int* deg     = alloci(N);
    int* rowptr  = alloci(N + 1);
    int* cursor  = alloci(N);
    int* perm    = alloci(E);
    int* snd_s   = alloci(E);
    float* s     = allocf((size_t)N * 64);
    float* v     = allocf((size_t)N * 192);
    float* agg0  = allocf((size_t)N * 64);   // also reused in-place as ms
    float* agg1  = allocf((size_t)N * 192);  // also reused in-place as mv
    float* sc_s  = allocf((size_t)N * 64);
    float* sc_v  = allocf((size_t)N * 192);
    float* geo   = allocf((size_t)E * 4);
    float* efT   = allocf((size_t)E * 8);
    float* pack  = allocf((size_t)N * 256);
    const int cap = (E / NCHUNK) * 3 / 2 + 256;  // chunk capacity with ~50% slack
    float* msg   = allocf((size_t)cap * 256);
    (void)ws_size; (void)n_in; (void)out_size;

    const int NT = (N + 63) / 64;
    const int ET = (E + 63) / 64;
    const int EB = (E + 255) / 256;

    k_init<<<NT, 64, 0, stream>>>(node_attrs, W_embed, species, deg, s, v, N);
    k_hist<<<EB, 256, 0, stream>>>(ei, deg, E);
    k_scan<<<1, 1024, 0, stream>>>(deg, rowptr, cursor, N);
    k_perm<<<EB, 256, 0, stream>>>(ei, cursor, perm, E);
    k_geom<<<ET, 64, 0, stream>>>(ei, perm, atom_pos, shifts,
                                  (float4*)geo, efT, snd_s, E);

    int nbound[NCHUNK + 1];
    for (int k = 0; k <= NCHUNK; k++) nbound[k] = (int)((long long)N * k / NCHUNK);

    for (int i = 0; i < L; i++) {
        // s_up/v_up -> packed float4 per (node, channel)
        k_4mv<<<NT, 64, 0, stream>>>(s, v, Wup_s + (size_t)i * 4096, Wup_v + (size_t)i * 4096,
                                     nullptr, nullptr, pack, N);
        for (int k = 0; k < NCHUNK; k++) {
            int na = nbound[k], nb = nbound[k + 1];
            k_msg<<<ET, 64, 0, stream>>>(rowptr, na, nb, efT, (const float4*)geo, snd_s,
                                         (const float4*)pack,
                                         RW1 + (size_t)i * 512, RW2 + (size_t)i * 4096,
                                         RW3 + (size_t)i * 20480, (float4*)msg, cap, E);
            int cnt = nb - na;
            k_agg<<<(cnt + 3) / 4, 256, 0, stream>>>((const float4*)msg, rowptr,
                                                     agg0, agg1, na, nb, cap);
        }
        k_sc<<<N, 64, 0, stream>>>(s, v, species, Wsc_s + (size_t)i * 40960,
                                   Wsc_v + (size_t)i * 40960, sc_s, sc_v, N);
        // ms = agg0 @ Wout_s (in place), mv = agg1 @ Wout_v (in place)
        k_4mv<<<NT, 64, 0, stream>>>(agg0, agg1, Wout_s + (size_t)i * 4096,
                                     Wout_v + (size_t)i * 4096, agg0, agg1, nullptr, N);
        k_prod_s<<<NT, 64, 0, stream>>>(agg0, agg1, P0 + (size_t)i * 1920, species,
                                        Wprod_s + (size_t)i * 4096, sc_s, s, out, N, i, L);
        k_prod_v<<<NT, 64, 0, stream>>>(agg0, agg1, P1 + (size_t)i * 1280, species,
                                        Wprod_v + (size_t)i * 4096, sc_v, v, N);
    }
}

// Round 3
// 2812.496 us; speedup vs baseline: 1.2835x; 1.2835x over previous
//
#include <hip/hip_runtime.h>
#include <hip/hip_bf16.h>
#include <hip/hip_fp16.h>

#define NCHUNK 3

__device__ __forceinline__ float siluf(float x) {
    return x / (1.0f + __expf(-x));
}

// ---------------- init: species + s = W_embed[z], v = 0, deg = 0 ----------------
__global__ void k_init(const float* __restrict__ attrs, const float* __restrict__ Wemb,
                       int* __restrict__ species, int* __restrict__ deg,
                       float* __restrict__ s, float* __restrict__ v, int N) {
    int lane = threadIdx.x;
    int n0 = blockIdx.x * 64;
    for (int r = 0; r < 64; r++) {
        int n = n0 + r;
        if (n >= N) break;
        float a = (lane < 10) ? attrs[n * 10 + lane] : 0.0f;
        unsigned long long m = __ballot(a > 0.5f);
        int z = __ffsll(m) - 1;
        if (lane == 0) { species[n] = z; deg[n] = 0; }
        s[n * 64 + lane] = Wemb[z * 64 + lane];
        v[n * 192 + lane] = 0.0f;
        v[n * 192 + 64 + lane] = 0.0f;
        v[n * 192 + 128 + lane] = 0.0f;
    }
}

// ---------------- counting sort by receiver ----------------
__global__ void k_hist(const int* __restrict__ ei, int* __restrict__ deg, int E) {
    int e = blockIdx.x * 256 + threadIdx.x;
    if (e < E) atomicAdd(&deg[ei[E + e]], 1);
}

__global__ void k_scan(const int* __restrict__ deg, int* __restrict__ rowptr,
                       int* __restrict__ cursor, int N) {
    __shared__ int part[1024];
    int t = threadIdx.x;
    int chunk = (N + 1023) / 1024;
    int lo = t * chunk, hi = min(lo + chunk, N);
    int sum = 0;
    for (int i = lo; i < hi; i++) sum += deg[i];
    part[t] = sum;
    __syncthreads();
    for (int off = 1; off < 1024; off <<= 1) {
        int add = (t >= off) ? part[t - off] : 0;
        __syncthreads();
        part[t] += add;
        __syncthreads();
    }
    int run = (t > 0) ? part[t - 1] : 0;
    for (int i = lo; i < hi; i++) { rowptr[i] = run; cursor[i] = run; run += deg[i]; }
    if (t == 1023) rowptr[N] = part[1023];
}

__global__ void k_perm(const int* __restrict__ ei, int* __restrict__ cursor,
                       int* __restrict__ perm, int E) {
    int e = blockIdx.x * 256 + threadIdx.x;
    if (e < E) {
        int r = ei[E + e];
        int pos = atomicAdd(&cursor[r], 1);
        perm[pos] = e;
    }
}

// ---------------- geometry + radial basis on SORTED edge order ----------------
__global__ void k_geom(const int* __restrict__ ei, const int* __restrict__ perm,
                       const float* __restrict__ pos, const float* __restrict__ shifts,
                       float4* __restrict__ geo, float* __restrict__ efT,
                       int* __restrict__ snd_s, int E) {
    int j = blockIdx.x * 64 + threadIdx.x;
    if (j >= E) return;
    int e = perm[j];
    int snd = ei[e], rcv = ei[E + e];
    float dx = pos[rcv * 3 + 0] - pos[snd * 3 + 0] + shifts[e * 3 + 0];
    float dy = pos[rcv * 3 + 1] - pos[snd * 3 + 1] + shifts[e * 3 + 1];
    float dz = pos[rcv * 3 + 2] - pos[snd * 3 + 2] + shifts[e * 3 + 2];
    float r = sqrtf(dx * dx + dy * dy + dz * dz);
    float rin = 1.0f / (r + 1e-9f);
    const float SQ3 = 1.7320508075688772f;
    geo[j] = make_float4(SQ3 * dx * rin, SQ3 * dy * rin, SQ3 * dz * rin, 0.0f);
    snd_s[j] = snd;
    float u = r * 0.2f;
    float env = 0.0f;
    if (u < 1.0f) {
        float u2 = u * u;
        float u6 = u2 * u2 * u2;
        env = 1.0f - 28.0f * u6 + 48.0f * u6 * u - 21.0f * u6 * u2;
    }
    const float PIF = 3.14159265358979f;
    float x = PIF * u;
    float sp = __sinf(x), cp = __cosf(x);
    float coef = 0.6324555320336759f * rin * env;
    float sm1 = 0.0f, scur = sp, twoc = 2.0f * cp;
    #pragma unroll
    for (int k = 0; k < 8; k++) {
        efT[k * (size_t)E + j] = coef * scur;
        float nxt = twoc * scur - sm1;
        sm1 = scur; scur = nxt;
    }
}

// ---------------- generic 64-node tile GEMV ----------------
__device__ __forceinline__ void tile_mv64(const float* __restrict__ in, int istride,
                                          const float* __restrict__ W,
                                          float* __restrict__ outp, int ostride,
                                          float* __restrict__ packf, int comp,
                                          int n0, int nv, float* lds, int lane) {
    for (int r = 0; r < nv; r++) lds[r * 65 + lane] = in[(size_t)(n0 + r) * istride + lane];
    __syncthreads();
    float acc[64];
    #pragma unroll
    for (int d = 0; d < 64; d++) acc[d] = 0.0f;
    for (int c = 0; c < 64; c++) {
        float x = lds[lane * 65 + c];
        const float* wr = W + c * 64;
        #pragma unroll
        for (int d = 0; d < 64; d++) acc[d] = fmaf(x, wr[d], acc[d]);
    }
    __syncthreads();
    #pragma unroll
    for (int d = 0; d < 64; d++) lds[lane * 65 + d] = acc[d];
    __syncthreads();
    for (int r = 0; r < nv; r++) {
        float val = lds[r * 65 + lane];
        if (outp) outp[(size_t)(n0 + r) * ostride + lane] = val;
        if (packf) packf[(((size_t)(n0 + r)) * 64 + lane) * 4 + comp] = val;
    }
    __syncthreads();
}

// 4 GEMVs: s @ Ws and v[x] @ Wv; optionally into packed float4 layout
__global__ void k_4mv(const float* __restrict__ ins, const float* __restrict__ inv,
                      const float* __restrict__ Ws, const float* __restrict__ Wv,
                      float* __restrict__ outs, float* __restrict__ outv,
                      float* __restrict__ packf, int N) {
    __shared__ float lds[64 * 65];
    int lane = threadIdx.x;
    int n0 = blockIdx.x * 64;
    int nv = min(64, N - n0);
    tile_mv64(ins, 64, Ws, outs, 64, packf, 0, n0, nv, lds, lane);
    for (int x = 0; x < 3; x++)
        tile_mv64(inv + x * 64, 192, Wv, outv ? outv + x * 64 : nullptr, 192,
                  packf, 1 + x, n0, nv, lds, lane);
}

// ---------------- message kernel: radial MLP + message -> fp16 coalesced store --------
__global__ void k_msg(const int* __restrict__ rowptr, int na, int nb,
                      const float* __restrict__ efT, const float4* __restrict__ geo,
                      const int* __restrict__ snd_s, const float4* __restrict__ pack,
                      const float* __restrict__ RW1, const float* __restrict__ RW2,
                      const float* __restrict__ RW3, float2* __restrict__ msg,
                      int cap, int E) {
    __shared__ float lh[64 * 64];
    __shared__ float lw[64 * 41];
    const int lane = threadIdx.x;
    const int Jlo = rowptr[na], Jhi = rowptr[nb];
    const int j0 = Jlo + blockIdx.x * 64;
    if (j0 >= Jhi) return;
    const int j = j0 + lane;
    const bool vj = (j < Jhi);

    float ef[8];
    #pragma unroll
    for (int k = 0; k < 8; k++) ef[k] = vj ? efT[k * (size_t)E + j] : 0.0f;
    float h[64];
    #pragma unroll
    for (int d = 0; d < 64; d++) h[d] = 0.0f;
    #pragma unroll
    for (int k = 0; k < 8; k++) {
        float x = ef[k];
        const float* wr = RW1 + k * 64;
        #pragma unroll
        for (int d = 0; d < 64; d++) h[d] = fmaf(x, wr[d], h[d]);
    }
    #pragma unroll
    for (int d = 0; d < 64; d++) lh[d * 64 + lane] = siluf(h[d]);
    __syncthreads();

    #pragma unroll
    for (int d = 0; d < 64; d++) h[d] = 0.0f;
    for (int c = 0; c < 64; c++) {
        float x = lh[c * 64 + lane];
        const float* wr = RW2 + c * 64;
        #pragma unroll
        for (int d = 0; d < 64; d++) h[d] = fmaf(x, wr[d], h[d]);
    }
    __syncthreads();
    #pragma unroll
    for (int d = 0; d < 64; d++) lh[d * 64 + lane] = siluf(h[d]);
    __syncthreads();

    const float inv32 = 1.0f / 32.0f;
    const float is3 = 0.5773502691896258f;
    const float is2 = 0.7071067811865476f;
    const int elb = lane >> 3;
    const int cj = lane & 7;

    for (int cc = 0; cc < 8; cc++) {
        float w[40];
        #pragma unroll
        for (int q = 0; q < 40; q++) w[q] = 0.0f;
        for (int c = 0; c < 64; c++) {
            float x = lh[c * 64 + lane];
            const float* wr = RW3 + c * 320 + cc * 8;
            #pragma unroll
            for (int q = 0; q < 5; q++) {
                #pragma unroll
                for (int jj = 0; jj < 8; jj++)
                    w[q * 8 + jj] = fmaf(x, wr[q * 64 + jj], w[q * 8 + jj]);
            }
        }
        __syncthreads();
        #pragma unroll
        for (int q = 0; q < 5; q++) {
            #pragma unroll
            for (int jj = 0; jj < 8; jj++)
                lw[lane * 41 + q * 8 + jj] = w[q * 8 + jj];
        }
        __syncthreads();

        const int c = cc * 8 + cj;
        for (int t = 0; t < 8; t++) {
            int el = t * 8 + elb;
            int e2 = j0 + el;
            if (e2 < Jhi && (e2 - Jlo) < cap) {
                int snd = snd_s[e2];
                float4 g = geo[e2];
                float w00  = lw[el * 41 + cj];
                float w110 = lw[el * 41 + 8 + cj];
                float w011 = lw[el * 41 + 16 + cj];
                float w101 = lw[el * 41 + 24 + cj];
                float w111 = lw[el * 41 + 32 + cj];
                float4 pv = pack[(size_t)snd * 64 + c];  // (s_up, v0, v1, v2)
                float dvy = pv.y * g.x + pv.z * g.y + pv.w * g.z;
                float m0 = (w00 * pv.x + w110 * dvy * is3) * inv32;
                float cxv = pv.z * g.z - pv.w * g.y;
                float cyv = pv.w * g.x - pv.y * g.z;
                float czv = pv.y * g.y - pv.z * g.x;
                float m1x = (w011 * pv.x * g.x + w101 * pv.y + w111 * cxv * is2) * inv32;
                float m1y = (w011 * pv.x * g.y + w101 * pv.z + w111 * cyv * is2) * inv32;
                float m1z = (w011 * pv.x * g.z + w101 * pv.w + w111 * czv * is2) * inv32;
                union { __half2 h; float f; } ua, ub;
                ua.h = __floats2half2_rn(m0, m1x);
                ub.h = __floats2half2_rn(m1y, m1z);
                msg[((size_t)(e2 - Jlo)) * 64 + c] = make_float2(ua.f, ub.f);
            }
        }
        __syncthreads();
    }
}

// ---------------- CSR aggregation: wave per node, lane = channel ----------------
__global__ void k_agg(const float2* __restrict__ msg, const int* __restrict__ rowptr,
                      float* __restrict__ agg0, float* __restrict__ agg1,
                      int na, int nb, int cap) {
    int n = na + blockIdx.x * 4 + (threadIdx.x >> 6);
    int lane = threadIdx.x & 63;
    if (n >= nb) return;
    int Jlo = rowptr[na];
    int j0 = rowptr[n], j1 = rowptr[n + 1];
    float a0 = 0.0f, a1 = 0.0f, a2 = 0.0f, a3 = 0.0f;
    for (int j = j0; j < j1; j++) {
        int idx = j - Jlo;
        if (idx >= cap) break;
        float2 m = msg[(size_t)idx * 64 + lane];
        union { float f; __half2 h; } ua, ub;
        ua.f = m.x; ub.f = m.y;
        float2 fa = __half22float2(ua.h);
        float2 fb = __half22float2(ub.h);
        a0 += fa.x; a1 += fa.y; a2 += fb.x; a3 += fb.y;
    }
    size_t nbase = (size_t)n;
    agg0[nbase * 64 + lane] = a0;
    agg1[nbase * 192 + lane] = a1;
    agg1[nbase * 192 + 64 + lane] = a2;
    agg1[nbase * 192 + 128 + lane] = a3;
}

// ---------------- species-dependent skip connections (wave = node) ----------------
__global__ void k_sc(const float* __restrict__ s, const float* __restrict__ v,
                     const int* __restrict__ species, const float* __restrict__ Wsc_s,
                     const float* __restrict__ Wsc_v, float* __restrict__ sc_s,
                     float* __restrict__ sc_v, int N) {
    int n = blockIdx.x;
    if (n >= N) return;
    int lane = threadIdx.x;
    int z = species[n];
    const float* Ws = Wsc_s + (size_t)z * 4096;
    const float* Wv = Wsc_v + (size_t)z * 4096;
    size_t nb = (size_t)n;
    float sreg = s[nb * 64 + lane];
    float acc = 0.0f;
    for (int c = 0; c < 64; c++)
        acc = fmaf(__shfl(sreg, c), Ws[c * 64 + lane], acc);
    sc_s[nb * 64 + lane] = acc;
    for (int x = 0; x < 3; x++) {
        float vreg = v[nb * 192 + x * 64 + lane];
        float av = 0.0f;
        for (int c = 0; c < 64; c++)
            av = fmaf(__shfl(vreg, c), Wv[c * 64 + lane], av);
        sc_v[nb * 192 + x * 64 + lane] = av;
    }
}

// ---------------- prod_s -> new s + output slot ----------------
__global__ void k_prod_s(const float* __restrict__ ms, const float* __restrict__ mv,
                         const float* __restrict__ P0l, const int* __restrict__ species,
                         const float* __restrict__ Wp, const float* __restrict__ sc_s,
                         float* __restrict__ s, float* __restrict__ out,
                         int N, int layer, int L) {
    __shared__ float lds[64 * 65];
    int lane = threadIdx.x;
    int n0 = blockIdx.x * 64;
    int nv = min(64, N - n0);
    for (int r = 0; r < nv; r++) {
        size_t n = n0 + r;
        int z = species[n];
        float msv = ms[n * 64 + lane];
        float a = mv[n * 192 + lane];
        float b = mv[n * 192 + 64 + lane];
        float cq = mv[n * 192 + 128 + lane];
        float mq = a * a + b * b + cq * cq;
        const float* p = P0l + ((size_t)z * 64 + lane) * 3;
        lds[r * 65 + lane] = p[0] * msv + p[1] * msv * msv + p[2] * mq;
    }
    __syncthreads();
    float acc[64];
    #pragma unroll
    for (int d = 0; d < 64; d++) acc[d] = 0.0f;
    for (int c = 0; c < 64; c++) {
        float x = lds[lane * 65 + c];
        const float* wr = Wp + c * 64;
        #pragma unroll
        for (int d = 0; d < 64; d++) acc[d] = fmaf(x, wr[d], acc[d]);
    }
    __syncthreads();
    #pragma unroll
    for (int d = 0; d < 64; d++) lds[lane * 65 + d] = acc[d];
    __syncthreads();
    for (int r = 0; r < nv; r++) {
        size_t n = n0 + r;
        float val = lds[r * 65 + lane] + sc_s[n * 64 + lane];
        s[n * 64 + lane] = val;
        out[n * (size_t)(L * 64) + layer * 64 + lane] = val;
    }
}

// ---------------- prod_v -> new v ----------------
__global__ void k_prod_v(const float* __restrict__ ms, const float* __restrict__ mv,
                         const float* __restrict__ P1l, const int* __restrict__ species,
                         const float* __restrict__ Wp, const float* __restrict__ sc_v,
                         float* __restrict__ v, int N) {
    __shared__ float lds[64 * 65];
    int lane = threadIdx.x;
    int n0 = blockIdx.x * 64;
    int nv = min(64, N - n0);
    for (int x = 0; x < 3; x++) {
        for (int r = 0; r < nv; r++) {
            size_t n = n0 + r;
            int z = species[n];
            float msv = ms[n * 64 + lane];
            float mvv = mv[n * 192 + x * 64 + lane];
            const float* q = P1l + ((size_t)z * 64 + lane) * 2;
            lds[r * 65 + lane] = (q[0] + q[1] * msv) * mvv;
        }
        __syncthreads();
        float acc[64];
        #pragma unroll
        for (int d = 0; d < 64; d++) acc[d] = 0.0f;
        for (int c = 0; c < 64; c++) {
            float xx = lds[lane * 65 + c];
            const float* wr = Wp + c * 64;
            #pragma unroll
            for (int d = 0; d < 64; d++) acc[d] = fmaf(xx, wr[d], acc[d]);
        }
        __syncthreads();
        #pragma unroll
        for (int d = 0; d < 64; d++) lds[lane * 65 + d] = acc[d];
        __syncthreads();
        for (int r = 0; r < nv; r++) {
            size_t n = n0 + r;
            v[n * 192 + x * 64 + lane] = lds[r * 65 + lane] + sc_v[n * 192 + x * 64 + lane];
        }
        __syncthreads();
    }
}

extern "C" void kernel_launch(void* const* d_in, const int* in_sizes, int n_in,
                              void* d_out, int out_size, void* d_ws, size_t ws_size,
                              hipStream_t stream) {
    const float* node_attrs = (const float*)d_in[0];
    const float* atom_pos   = (const float*)d_in[1];
    const float* shifts     = (const float*)d_in[2];
    const float* W_embed    = (const float*)d_in[3];
    const float* Wup_s      = (const float*)d_in[4];
    const float* Wup_v      = (const float*)d_in[5];
    const float* RW1        = (const float*)d_in[6];
    const float* RW2        = (const float*)d_in[7];
    const float* RW3        = (const float*)d_in[8];
    const float* Wout_s     = (const float*)d_in[9];
    const float* Wout_v     = (const float*)d_in[10];
    const float* Wsc_s      = (const float*)d_in[11];
    const float* Wsc_v      = (const float*)d_in[12];
    const float* P0         = (const float*)d_in[13];
    const float* P1         = (const float*)d_in[14];
    const float* Wprod_s    = (const float*)d_in[15];
    const float* Wprod_v    = (const float*)d_in[16];
    const int*   ei         = (const int*)d_in[17];

    const int N = in_sizes[0] / 10;
    const int E = in_sizes[17] / 2;
    const int L = in_sizes[4] / 4096;
    float* out = (float*)d_out;

    char* wsb = (char*)d_ws;
    size_t off = 0;
    auto alloci = [&](size_t n) {
        int* p = (int*)(wsb + off);
        off = (off + n * 4 + 255) / 256 * 256;
        return p;
    };
    auto allocf = [&](size_t n) {
        float* p = (float*)(wsb + off);
        off = (off + n * 4 + 255) / 256 * 256;
        return p;
    };
    int* species = alloci(N);
    int* deg     = alloci(N);
    int* rowptr  = alloci(N + 1);
    int* cursor  = alloci(N);
    int* perm    = alloci(E);
    int* snd_s   = alloci(E);
    float* s     = allocf((size_t)N * 64);
    float* v     = allocf((size_t)N * 192);
    float* agg0  = allocf((size_t)N * 64);   // reused in-place as ms
    float* agg1  = allocf((size_t)N * 192);  // reused in-place as mv
    float* geo   = allocf((size_t)E * 4);
    float* efT   = allocf((size_t)E * 8);
    float* pack  = allocf((size_t)N * 256);
    // sc_s/sc_v alias pack: pack is dead after the last k_msg of a layer,
    // sc_* is written by k_sc (after) and read by k_prod_* (after). Sizes match exactly.
    float* sc_s  = pack;
    float* sc_v  = pack + (size_t)N * 64;
    const int cap = (E / NCHUNK) * 5 / 4 + 256;   // chunk edge capacity, ~25% slack
    float* msg   = allocf((size_t)cap * 128);     // fp16 half4 = float2 per (edge,ch)
    (void)ws_size; (void)n_in; (void)out_size;

    const int NT = (N + 63) / 64;
    const int ET = (E + 63) / 64;
    const int EB = (E + 255) / 256;
    const int MT = (cap + 63) / 64;               // k_msg grid per chunk

    k_init<<<NT, 64, 0, stream>>>(node_attrs, W_embed, species, deg, s, v, N);
    k_hist<<<EB, 256, 0, stream>>>(ei, deg, E);
    k_scan<<<1, 1024, 0, stream>>>(deg, rowptr, cursor, N);
    k_perm<<<EB, 256, 0, stream>>>(ei, cursor, perm, E);
    k_geom<<<ET, 64, 0, stream>>>(ei, perm, atom_pos, shifts,
                                  (float4*)geo, efT, snd_s, E);

    int nbound[NCHUNK + 1];
    for (int k = 0; k <= NCHUNK; k++) nbound[k] = (int)((long long)N * k / NCHUNK);

    for (int i = 0; i < L; i++) {
        k_4mv<<<NT, 64, 0, stream>>>(s, v, Wup_s + (size_t)i * 4096, Wup_v + (size_t)i * 4096,
                                     nullptr, nullptr, pack, N);
        for (int k = 0; k < NCHUNK; k++) {
            int na = nbound[k], nb = nbound[k + 1];
            k_msg<<<MT, 64, 0, stream>>>(rowptr, na, nb, efT, (const float4*)geo, snd_s,
                                         (const float4*)pack,
                                         RW1 + (size_t)i * 512, RW2 + (size_t)i * 4096,
                                         RW3 + (size_t)i * 20480, (float2*)msg, cap, E);
            int cnt = nb - na;
            k_agg<<<(cnt + 3) / 4, 256, 0, stream>>>((const float2*)msg, rowptr,
                                                     agg0, agg1, na, nb, cap);
        }
        k_sc<<<N, 64, 0, stream>>>(s, v, species, Wsc_s + (size_t)i * 40960,
                                   Wsc_v + (size_t)i * 40960, sc_s, sc_v, N);
        k_4mv<<<NT, 64, 0, stream>>>(agg0, agg1, Wout_s + (size_t)i * 4096,
                                     Wout_v + (size_t)i * 4096, agg0, agg1, nullptr, N);
        k_prod_s<<<NT, 64, 0, stream>>>(agg0, agg1, P0 + (size_t)i * 1920, species,
                                        Wprod_s + (size_t)i * 4096, sc_s, s, out, N, i, L);
        k_prod_v<<<NT, 64, 0, stream>>>(agg0, agg1, P1 + (size_t)i * 1280, species,
                                        Wprod_v + (size_t)i * 4096, sc_v, v, N);
    }
}